// Round 1
// baseline (406.204 us; speedup 1.0000x reference)
//
#include <hip/hip_runtime.h>
#include <cstdint>
#include <cstddef>

// GLA layer: B=4, T=4096, D=1024, H=16, S=64  (HS = 1024)
// y = (scan(sigmoid-gated recurrence)) @ out_w^T ; h_last
//
// Pipeline:
//  1. cast x, gate_w|value_w (combined 3072x1024), out_w to bf16
//  2. GEMM1 (bf16 MFMA): C[16384,3072] = x @ Wcomb^T, fused epilogue:
//       cols [0,1024)    -> a  = sigmoid(c + gate_b[m])      -> d_out (scratch)
//       cols [1024,2048) -> bg = sigmoid(c + gate_b[m])      -> ws.g1
//       cols [2048,3072) -> v  = c                           -> ws.v
//  3. chunked parallel scan over T (32 chunks x 128), fp32:
//       pass1: per-chunk (prod a, local scan end)  pass2: combine + h_last
//       pass3: write h as bf16 (into x_bf16 region, dead by then)
//  4. GEMM2 (bf16 MFMA): y[16384,1024] = h @ out_w^T -> d_out

typedef __bf16 bf16;
typedef __bf16 bf16x8 __attribute__((ext_vector_type(8)));
typedef float  f32x4  __attribute__((ext_vector_type(4)));

__device__ __forceinline__ void gload_lds16(const void* g, void* l) {
  __builtin_amdgcn_global_load_lds(
      (const __attribute__((address_space(1))) void*)g,
      (__attribute__((address_space(3))) void*)l, 16, 0, 0);
}

__device__ __forceinline__ float sigmoidf_(float x) {
  return 1.0f / (1.0f + __expf(-x));
}

// ---------------- cast fp32 -> bf16, 8 elems/thread ----------------
__global__ __launch_bounds__(256) void cast_f32_to_bf16(
    const float* __restrict__ src, bf16* __restrict__ dst, int n8) {
  int i = blockIdx.x * 256 + threadIdx.x;
  if (i >= n8) return;
  const float4* s4 = (const float4*)src;
  float4 v0 = s4[2 * i], v1 = s4[2 * i + 1];
  bf16x8 o;
  o[0] = (bf16)v0.x; o[1] = (bf16)v0.y; o[2] = (bf16)v0.z; o[3] = (bf16)v0.w;
  o[4] = (bf16)v1.x; o[5] = (bf16)v1.y; o[6] = (bf16)v1.z; o[7] = (bf16)v1.w;
  *(bf16x8*)(dst + (size_t)i * 8) = o;
}

// ---------------- bf16 MFMA GEMM: C[N,M] = A[N,K] * B[M,K]^T ----------------
// 128x128 tile, BK=64, 4 waves (each 64x64 = 4x4 of 16x16x32 MFMA),
// global_load_lds width-16 staging with XOR k-chunk swizzle (2-way LDS max).
template <int MCOLS, int EPI>
__global__ __launch_bounds__(256, 3) void gemm_bt(
    const bf16* __restrict__ A, const bf16* __restrict__ Bw,
    const float* __restrict__ gate_b,
    float* __restrict__ o0, float* __restrict__ o1, float* __restrict__ o2) {
  constexpr int K = 1024;
  __shared__ __align__(16) bf16 As[128 * 64];
  __shared__ __align__(16) bf16 Bs[128 * 64];
  const int tid  = threadIdx.x;
  const int lane = tid & 63;
  const int quad = lane >> 4;
  const int wv   = tid >> 6;
  const int wrow = wv & 1, wcol = wv >> 1;
  const int n0 = blockIdx.y * 128;
  const int m0 = blockIdx.x * 128;

  const bf16* ga[4];
  const bf16* gb[4];
  bf16* la[4];
  bf16* lb[4];
#pragma unroll
  for (int j = 0; j < 4; ++j) {
    int s   = j * 256 + tid;           // 16B slot in [0,1024)
    int row = s >> 3;                  // tile row
    int kc  = (s & 7) ^ (row & 7);     // swizzled k-chunk (8 bf16)
    ga[j] = A  + (size_t)(n0 + row) * K + kc * 8;
    gb[j] = Bw + (size_t)(m0 + row) * K + kc * 8;
    la[j] = &As[s * 8];
    lb[j] = &Bs[s * 8];
  }

  f32x4 acc[4][4];
#pragma unroll
  for (int mi = 0; mi < 4; ++mi)
#pragma unroll
    for (int ni = 0; ni < 4; ++ni) acc[mi][ni] = (f32x4){0.f, 0.f, 0.f, 0.f};

  for (int k0 = 0; k0 < K; k0 += 64) {
#pragma unroll
    for (int j = 0; j < 4; ++j) gload_lds16(ga[j], la[j]);
#pragma unroll
    for (int j = 0; j < 4; ++j) gload_lds16(gb[j], lb[j]);
#pragma unroll
    for (int j = 0; j < 4; ++j) { ga[j] += 64; gb[j] += 64; }
    __syncthreads();  // drains vmcnt: staged data visible
#pragma unroll
    for (int kk = 0; kk < 2; ++kk) {
      bf16x8 af[4], bfv[4];
#pragma unroll
      for (int mi = 0; mi < 4; ++mi) {
        int row  = wrow * 64 + mi * 16 + (lane & 15);
        int slot = row * 8 + ((kk * 4 + quad) ^ (row & 7));
        af[mi] = *(const bf16x8*)(&As[slot * 8]);
      }
#pragma unroll
      for (int ni = 0; ni < 4; ++ni) {
        int row  = wcol * 64 + ni * 16 + (lane & 15);
        int slot = row * 8 + ((kk * 4 + quad) ^ (row & 7));
        bfv[ni] = *(const bf16x8*)(&Bs[slot * 8]);
      }
#pragma unroll
      for (int mi = 0; mi < 4; ++mi)
#pragma unroll
        for (int ni = 0; ni < 4; ++ni)
          acc[mi][ni] = __builtin_amdgcn_mfma_f32_16x16x32_bf16(
              af[mi], bfv[ni], acc[mi][ni], 0, 0, 0);
    }
    __syncthreads();  // all waves done reading before next overwrite
  }

  // epilogue: C/D layout col=lane&15, row=quad*4+r
#pragma unroll
  for (int mi = 0; mi < 4; ++mi) {
#pragma unroll
    for (int ni = 0; ni < 4; ++ni) {
      const int m = m0 + wcol * 64 + ni * 16 + (lane & 15);
#pragma unroll
      for (int r = 0; r < 4; ++r) {
        const int n = n0 + wrow * 64 + mi * 16 + quad * 4 + r;
        float val = acc[mi][ni][r];
        if (EPI == 0) {
          if (m < 2048) {
            float sv = sigmoidf_(val + gate_b[m]);
            if (m < 1024)
              o0[(size_t)n * 1024 + m] = sv;          // forget gate a
            else
              o1[(size_t)n * 1024 + (m - 1024)] = sv; // input gate bg
          } else {
            o2[(size_t)n * 1024 + (m - 2048)] = val;  // v
          }
        } else {
          o0[(size_t)n * MCOLS + m] = val;            // y
        }
      }
    }
  }
}

// ---------------- chunked parallel scan: h_t = a_t*h_{t-1} + bg_t*v_t -----
// T=4096 = 32 chunks x 128; channels = b*1024 + c (4096 total)
__global__ __launch_bounds__(256) void scan_pass1(
    const float* __restrict__ a, const float* __restrict__ bg,
    const float* __restrict__ v, float* __restrict__ Ac,
    float* __restrict__ Uc) {
  const int c = blockIdx.x * 256 + threadIdx.x;  // 0..1023
  const int j = blockIdx.y;                      // chunk 0..31
  const int b = blockIdx.z;                      // 0..3
  const size_t base = ((size_t)(b * 4096 + j * 128)) * 1024 + c;
  const float* pa = a + base;
  const float* pg = bg + base;
  const float* pv = v + base;
  float P = 1.f, U = 0.f;
#pragma unroll 4
  for (int t = 0; t < 128; ++t) {
    float at  = pa[(size_t)t * 1024];
    float bvt = pg[(size_t)t * 1024] * pv[(size_t)t * 1024];
    P *= at;
    U = at * U + bvt;
  }
  const size_t o = ((size_t)(b * 32 + j)) * 1024 + c;
  Ac[o] = P;
  Uc[o] = U;
}

__global__ __launch_bounds__(256) void scan_pass2(
    const float* __restrict__ Ac, const float* __restrict__ Uc,
    const float* __restrict__ h_prev, float* __restrict__ Hs,
    float* __restrict__ hlast) {
  const int id = blockIdx.x * 256 + threadIdx.x;  // 0..4095
  const int b = id >> 10, c = id & 1023;
  float H = h_prev[b * 1024 + c];
  for (int j = 0; j < 32; ++j) {
    const size_t o = ((size_t)(b * 32 + j)) * 1024 + c;
    Hs[o] = H;
    H = Ac[o] * H + Uc[o];
  }
  hlast[b * 1024 + c] = H;
}

__global__ __launch_bounds__(256) void scan_pass3(
    const float* __restrict__ a, const float* __restrict__ bg,
    const float* __restrict__ v, const float* __restrict__ Hs,
    bf16* __restrict__ hb) {
  const int c = blockIdx.x * 256 + threadIdx.x;
  const int j = blockIdx.y;
  const int b = blockIdx.z;
  const size_t base = ((size_t)(b * 4096 + j * 128)) * 1024 + c;
  const float* pa = a + base;
  const float* pg = bg + base;
  const float* pv = v + base;
  bf16* ph = hb + base;
  float h = Hs[((size_t)(b * 32 + j)) * 1024 + c];
#pragma unroll 4
  for (int t = 0; t < 128; ++t) {
    float at  = pa[(size_t)t * 1024];
    float bvt = pg[(size_t)t * 1024] * pv[(size_t)t * 1024];
    h = at * h + bvt;
    ph[(size_t)t * 1024] = (bf16)h;
  }
}

extern "C" void kernel_launch(void* const* d_in, const int* in_sizes, int n_in,
                              void* d_out, int out_size, void* d_ws,
                              size_t ws_size, hipStream_t stream) {
  const float* x       = (const float*)d_in[0];
  const float* h_prev  = (const float*)d_in[1];
  const float* gate_w  = (const float*)d_in[2];
  const float* gate_b  = (const float*)d_in[3];
  const float* value_w = (const float*)d_in[4];
  const float* out_w   = (const float*)d_in[5];
  float* out = (float*)d_out;

  char* ws = (char*)d_ws;
  // ws layout (bytes), total ~177.7 MB:
  bf16*  xb   = (bf16*)(ws);                    // 33,554,432  (reused as h bf16)
  bf16*  wgv  = (bf16*)(ws + 33554432);         //  6,291,456  gate_w|value_w
  bf16*  owb  = (bf16*)(ws + 39845888);         //  2,097,152  out_w
  float* g1   = (float*)(ws + 41943040);        // 67,108,864  bg
  float* vbuf = (float*)(ws + 109051904);       // 67,108,864  v
  float* Ac   = (float*)(ws + 176160768);       //    524,288
  float* Uc   = (float*)(ws + 176685056);       //    524,288
  float* Hs   = (float*)(ws + 177209344);       //    524,288
  bf16*  hb   = xb;          // x_bf16 dead after GEMM1
  float* abuf = out;         // y region of d_out as scratch for forget gate a
  float* hlast = out + 16777216;

  // casts
  cast_f32_to_bf16<<<8192, 256, 0, stream>>>(x, xb, 2097152);
  cast_f32_to_bf16<<<1024, 256, 0, stream>>>(gate_w, wgv, 262144);
  cast_f32_to_bf16<<<512, 256, 0, stream>>>(value_w, wgv + 2048 * 1024, 131072);
  cast_f32_to_bf16<<<512, 256, 0, stream>>>(out_w, owb, 131072);

  // gates + values GEMM with fused sigmoid epilogue
  gemm_bt<3072, 0><<<dim3(24, 128), 256, 0, stream>>>(xb, wgv, gate_b, abuf,
                                                      g1, vbuf);

  // chunked scan
  scan_pass1<<<dim3(4, 32, 4), 256, 0, stream>>>(abuf, g1, vbuf, Ac, Uc);
  scan_pass2<<<16, 256, 0, stream>>>(Ac, Uc, h_prev, Hs, hlast);
  scan_pass3<<<dim3(4, 32, 4), 256, 0, stream>>>(abuf, g1, vbuf, Hs, hb);

  // output GEMM
  gemm_bt<1024, 1><<<dim3(8, 128), 256, 0, stream>>>(hb, owb, nullptr, out,
                                                     nullptr, nullptr);
}

// Round 2
// 377.280 us; speedup vs baseline: 1.0767x; 1.0767x over previous
//
#include <hip/hip_runtime.h>
#include <cstdint>
#include <cstddef>

// GLA layer: B=4, T=4096, D=1024, H=16, S=64  (HS = 1024)
// fp16 pipeline: casts -> GEMM1 (fused sigmoid epilogue, fp16 outputs) ->
// chunked fp32 scan (fp16 storage) -> GEMM2 -> y fp32 + h_last fp32

typedef _Float16 f16;
typedef _Float16 f16x2 __attribute__((ext_vector_type(2)));
typedef _Float16 f16x8 __attribute__((ext_vector_type(8)));
typedef float    f32x4 __attribute__((ext_vector_type(4)));

__device__ __forceinline__ void gload_lds16(const void* g, void* l) {
  __builtin_amdgcn_global_load_lds(
      (const __attribute__((address_space(1))) void*)g,
      (__attribute__((address_space(3))) void*)l, 16, 0, 0);
}

__device__ __forceinline__ float sigmoidf_(float x) {
  return 1.0f / (1.0f + __expf(-x));
}

// ---------------- cast fp32 -> fp16, 8 elems/thread ----------------
__global__ __launch_bounds__(256) void cast_f32_to_f16(
    const float* __restrict__ src, f16* __restrict__ dst, int n8) {
  int i = blockIdx.x * 256 + threadIdx.x;
  if (i >= n8) return;
  const float4* s4 = (const float4*)src;
  float4 v0 = s4[2 * i], v1 = s4[2 * i + 1];
  f16x8 o;
  o[0] = (f16)v0.x; o[1] = (f16)v0.y; o[2] = (f16)v0.z; o[3] = (f16)v0.w;
  o[4] = (f16)v1.x; o[5] = (f16)v1.y; o[6] = (f16)v1.z; o[7] = (f16)v1.w;
  *(f16x8*)(dst + (size_t)i * 8) = o;
}

// ---------------- fp16 MFMA GEMM: C[N,M] = A[N,K] * B[M,K]^T ----------------
// 128x128 tile, BK=64, 4 waves (each 64x64 = 4x4 of 16x16x32 MFMA),
// global_load_lds width-16 staging with XOR k-chunk swizzle.
// EPI 0: cols [0,1024)->sigmoid->o0 (f16), [1024,2048)->sigmoid->o1 (f16),
//        [2048,3072)->o2 (f16).   EPI 1: o0 fp32 y [N,1024].
template <int EPI>
__global__ __launch_bounds__(256, 3) void gemm_bt(
    const f16* __restrict__ A, const f16* __restrict__ Bw,
    const float* __restrict__ gate_b,
    void* __restrict__ o0v, void* __restrict__ o1v, void* __restrict__ o2v) {
  constexpr int K = 1024;
  __shared__ __align__(16) f16 As[128 * 64];
  __shared__ __align__(16) f16 Bs[128 * 64];
  const int tid  = threadIdx.x;
  const int lane = tid & 63;
  const int quad = lane >> 4;
  const int wv   = tid >> 6;
  const int wrow = wv & 1, wcol = wv >> 1;
  const int n0 = blockIdx.y * 128;
  const int m0 = blockIdx.x * 128;

  const f16* ga[4];
  const f16* gb[4];
  f16* la[4];
  f16* lb[4];
#pragma unroll
  for (int j = 0; j < 4; ++j) {
    int s   = j * 256 + tid;           // 16B slot in [0,1024)
    int row = s >> 3;                  // tile row
    int kc  = (s & 7) ^ (row & 7);     // swizzled k-chunk (8 f16)
    ga[j] = A  + (size_t)(n0 + row) * K + kc * 8;
    gb[j] = Bw + (size_t)(m0 + row) * K + kc * 8;
    la[j] = &As[s * 8];
    lb[j] = &Bs[s * 8];
  }

  f32x4 acc[4][4];
#pragma unroll
  for (int mi = 0; mi < 4; ++mi)
#pragma unroll
    for (int ni = 0; ni < 4; ++ni) acc[mi][ni] = (f32x4){0.f, 0.f, 0.f, 0.f};

  for (int k0 = 0; k0 < K; k0 += 64) {
#pragma unroll
    for (int j = 0; j < 4; ++j) gload_lds16(ga[j], la[j]);
#pragma unroll
    for (int j = 0; j < 4; ++j) gload_lds16(gb[j], lb[j]);
#pragma unroll
    for (int j = 0; j < 4; ++j) { ga[j] += 64; gb[j] += 64; }
    __syncthreads();
#pragma unroll
    for (int kk = 0; kk < 2; ++kk) {
      f16x8 af[4], bfv[4];
#pragma unroll
      for (int mi = 0; mi < 4; ++mi) {
        int row  = wrow * 64 + mi * 16 + (lane & 15);
        int slot = row * 8 + ((kk * 4 + quad) ^ (row & 7));
        af[mi] = *(const f16x8*)(&As[slot * 8]);
      }
#pragma unroll
      for (int ni = 0; ni < 4; ++ni) {
        int row  = wcol * 64 + ni * 16 + (lane & 15);
        int slot = row * 8 + ((kk * 4 + quad) ^ (row & 7));
        bfv[ni] = *(const f16x8*)(&Bs[slot * 8]);
      }
#pragma unroll
      for (int mi = 0; mi < 4; ++mi)
#pragma unroll
        for (int ni = 0; ni < 4; ++ni)
          acc[mi][ni] = __builtin_amdgcn_mfma_f32_16x16x32_f16(
              af[mi], bfv[ni], acc[mi][ni], 0, 0, 0);
    }
    __syncthreads();
  }

  // epilogue: C/D layout col=lane&15, row=quad*4+r
#pragma unroll
  for (int mi = 0; mi < 4; ++mi) {
#pragma unroll
    for (int ni = 0; ni < 4; ++ni) {
      const int m = m0 + wcol * 64 + ni * 16 + (lane & 15);
#pragma unroll
      for (int r = 0; r < 4; ++r) {
        const int n = n0 + wrow * 64 + mi * 16 + quad * 4 + r;
        float val = acc[mi][ni][r];
        if (EPI == 0) {
          if (m < 2048) {
            f16 sv = (f16)sigmoidf_(val + gate_b[m]);
            if (m < 1024)
              ((f16*)o0v)[(size_t)n * 1024 + m] = sv;          // forget a
            else
              ((f16*)o1v)[(size_t)n * 1024 + (m - 1024)] = sv; // input bg
          } else {
            ((f16*)o2v)[(size_t)n * 1024 + (m - 2048)] = (f16)val;  // v
          }
        } else {
          ((float*)o0v)[(size_t)n * 1024 + m] = val;           // y
        }
      }
    }
  }
}

// ---------------- chunked parallel scan: h_t = a_t*h_{t-1} + bg_t*v_t -----
// T=4096 = 32 chunks x 128; 2 channels/thread via f16x2.
__global__ __launch_bounds__(256) void scan_pass1(
    const f16x2* __restrict__ a, const f16x2* __restrict__ bg,
    const f16x2* __restrict__ v, float2* __restrict__ Ac,
    float2* __restrict__ Uc) {
  const int c2 = blockIdx.x * 256 + threadIdx.x;  // 0..511
  const int j = blockIdx.y;                       // chunk 0..31
  const int b = blockIdx.z;                       // 0..3
  const size_t base = ((size_t)(b * 4096 + j * 128)) * 512 + c2;
  float P0 = 1.f, P1 = 1.f, U0 = 0.f, U1 = 0.f;
#pragma unroll 4
  for (int t = 0; t < 128; ++t) {
    const size_t o = base + (size_t)t * 512;
    f16x2 at = a[o], gt = bg[o], vt = v[o];
    float a0 = (float)at[0], a1 = (float)at[1];
    float bv0 = (float)gt[0] * (float)vt[0];
    float bv1 = (float)gt[1] * (float)vt[1];
    P0 *= a0; P1 *= a1;
    U0 = a0 * U0 + bv0;
    U1 = a1 * U1 + bv1;
  }
  const size_t o = ((size_t)(b * 32 + j)) * 512 + c2;
  Ac[o] = make_float2(P0, P1);
  Uc[o] = make_float2(U0, U1);
}

__global__ __launch_bounds__(256) void scan_pass2(
    const float* __restrict__ Ac, const float* __restrict__ Uc,
    const float* __restrict__ h_prev, float* __restrict__ Hs,
    float* __restrict__ hlast) {
  const int id = blockIdx.x * 256 + threadIdx.x;  // 0..4095
  const int b = id >> 10, c = id & 1023;
  float H = h_prev[b * 1024 + c];
  for (int j = 0; j < 32; ++j) {
    const size_t o = ((size_t)(b * 32 + j)) * 1024 + c;
    Hs[o] = H;
    H = Ac[o] * H + Uc[o];
  }
  hlast[b * 1024 + c] = H;
}

__global__ __launch_bounds__(256) void scan_pass3(
    const f16x2* __restrict__ a, const f16x2* __restrict__ bg,
    const f16x2* __restrict__ v, const float2* __restrict__ Hs,
    f16x2* __restrict__ hb) {
  const int c2 = blockIdx.x * 256 + threadIdx.x;
  const int j = blockIdx.y;
  const int b = blockIdx.z;
  const size_t base = ((size_t)(b * 4096 + j * 128)) * 512 + c2;
  float2 H = Hs[((size_t)(b * 32 + j)) * 512 + c2];
  float h0 = H.x, h1 = H.y;
#pragma unroll 4
  for (int t = 0; t < 128; ++t) {
    const size_t o = base + (size_t)t * 512;
    f16x2 at = a[o], gt = bg[o], vt = v[o];
    float a0 = (float)at[0], a1 = (float)at[1];
    h0 = a0 * h0 + (float)gt[0] * (float)vt[0];
    h1 = a1 * h1 + (float)gt[1] * (float)vt[1];
    f16x2 hv; hv[0] = (f16)h0; hv[1] = (f16)h1;
    hb[o] = hv;
  }
}

extern "C" void kernel_launch(void* const* d_in, const int* in_sizes, int n_in,
                              void* d_out, int out_size, void* d_ws,
                              size_t ws_size, hipStream_t stream) {
  const float* x       = (const float*)d_in[0];
  const float* h_prev  = (const float*)d_in[1];
  const float* gate_w  = (const float*)d_in[2];
  const float* gate_b  = (const float*)d_in[3];
  const float* value_w = (const float*)d_in[4];
  const float* out_w   = (const float*)d_in[5];
  float* out = (float*)d_out;

  char* ws = (char*)d_ws;
  // ws layout (bytes), total ~144.2 MB:
  f16*   xh   = (f16*)(ws);                     // 33,554,432  x f16; reused as h f16
  f16*   wgv  = (f16*)(ws + 33554432);          //  6,291,456  gate_w|value_w f16
  f16*   owb  = (f16*)(ws + 39845888);          //  2,097,152  out_w f16
  f16*   abuf = (f16*)(ws + 41943040);          // 33,554,432  forget gate a
  f16*   g1   = (f16*)(ws + 75497472);          // 33,554,432  input gate bg
  f16*   vbuf = (f16*)(ws + 109051904);         // 33,554,432  v
  float* Ac   = (float*)(ws + 142606336);       //    524,288
  float* Uc   = (float*)(ws + 143130624);       //    524,288
  float* Hs   = (float*)(ws + 143654912);       //    524,288
  float* hlast = out + 16777216;

  // casts
  cast_f32_to_f16<<<8192, 256, 0, stream>>>(x, xh, 2097152);
  cast_f32_to_f16<<<1024, 256, 0, stream>>>(gate_w, wgv, 262144);
  cast_f32_to_f16<<<512, 256, 0, stream>>>(value_w, wgv + 2048 * 1024, 131072);
  cast_f32_to_f16<<<512, 256, 0, stream>>>(out_w, owb, 131072);

  // gates + values GEMM with fused sigmoid epilogue (fp16 outputs)
  gemm_bt<0><<<dim3(24, 128), 256, 0, stream>>>(xh, wgv, gate_b, abuf, g1,
                                                vbuf);

  // chunked scan (fp32 math, fp16 storage)
  scan_pass1<<<dim3(2, 32, 4), 256, 0, stream>>>(
      (const f16x2*)abuf, (const f16x2*)g1, (const f16x2*)vbuf, (float2*)Ac,
      (float2*)Uc);
  scan_pass2<<<16, 256, 0, stream>>>(Ac, Uc, h_prev, Hs, hlast);
  scan_pass3<<<dim3(2, 32, 4), 256, 0, stream>>>(
      (const f16x2*)abuf, (const f16x2*)g1, (const f16x2*)vbuf,
      (const float2*)Hs, (f16x2*)xh);

  // output GEMM -> y fp32
  gemm_bt<1><<<dim3(8, 128), 256, 0, stream>>>(xh, owb, nullptr, out, nullptr,
                                               nullptr);
}

// Round 3
// 373.328 us; speedup vs baseline: 1.0881x; 1.0106x over previous
//
#include <hip/hip_runtime.h>
#include <cstdint>
#include <cstddef>

// GLA layer: B=4, T=4096, D=1024, H=16, S=64
// fp16 pipeline, packed weights:
//   Wcomb rows [0,1024)        = gate_a rows (forget gate)
//   Wcomb rows 1024+2c / +2c+1 = gate_b row c / value row c (interleaved)
// GEMM1 epilogue computes a = sigmoid(.) and bv = sigmoid(.)*v in-register
// (lane-pair shfl), stages tiles in LDS, stores coalesced f16x8.
// Scan: 128 chunks x 32 steps, fp32 math / f16 storage. GEMM2 -> y fp32.

typedef _Float16 f16;
typedef _Float16 f16x2 __attribute__((ext_vector_type(2)));
typedef _Float16 f16x8 __attribute__((ext_vector_type(8)));
typedef float    f32x4 __attribute__((ext_vector_type(4)));

__device__ __forceinline__ void gload_lds16(const void* g, void* l) {
  __builtin_amdgcn_global_load_lds(
      (const __attribute__((address_space(1))) void*)g,
      (__attribute__((address_space(3))) void*)l, 16, 0, 0);
}

__device__ __forceinline__ float sigmoidf_(float x) {
  return 1.0f / (1.0f + __expf(-x));
}

// ---------------- fused cast+pack fp32 -> fp16 ----------------
__global__ __launch_bounds__(256) void cast_pack(
    const float* __restrict__ x, const float* __restrict__ gw,
    const float* __restrict__ vw, const float* __restrict__ ow,
    f16* __restrict__ xh, f16* __restrict__ wgv, f16* __restrict__ owb) {
  const int XG = 2097152, GG = 262144, VG = 131072, OG = 131072;
  int id = blockIdx.x * 256 + threadIdx.x;
  const float* src;
  f16* dst;
  if (id < XG) {
    src = x + (size_t)id * 8;
    dst = xh + (size_t)id * 8;
  } else if (id < XG + GG) {
    int g = id - XG;
    int row = g >> 7, col = g & 127;
    int drow = (row < 1024) ? row : (1024 + 2 * (row - 1024));
    src = gw + ((size_t)row << 10) + col * 8;
    dst = wgv + ((size_t)drow << 10) + col * 8;
  } else if (id < XG + GG + VG) {
    int g = id - XG - GG;
    int row = g >> 7, col = g & 127;
    int drow = 1024 + 2 * row + 1;
    src = vw + ((size_t)row << 10) + col * 8;
    dst = wgv + ((size_t)drow << 10) + col * 8;
  } else if (id < XG + GG + VG + OG) {
    int g = id - XG - GG - VG;
    src = ow + (size_t)g * 8;
    dst = owb + (size_t)g * 8;
  } else {
    return;
  }
  float4 v0 = ((const float4*)src)[0], v1 = ((const float4*)src)[1];
  f16x8 o;
  o[0] = (f16)v0.x; o[1] = (f16)v0.y; o[2] = (f16)v0.z; o[3] = (f16)v0.w;
  o[4] = (f16)v1.x; o[5] = (f16)v1.y; o[6] = (f16)v1.z; o[7] = (f16)v1.w;
  *(f16x8*)dst = o;
}

// ---------------- fp16 MFMA GEMM: C[N,M] = A[N,K] * B[M,K]^T ----------------
// 128x128 tile, BK=64, 4 waves (64x64 each = 4x4 of 16x16x32 MFMA).
// EPI 0: m0<1024 -> a=sigmoid(c+bias) f16 to o0; m0>=1024 -> paired cols,
//        bv=sigmoid(bg+bias)*v f16 to o1 (64 channels/tile). LDS-staged stores.
// EPI 1: o0 fp32 y [N,1024], direct stores.
template <int EPI>
__global__ __launch_bounds__(256, 3) void gemm_bt(
    const f16* __restrict__ A, const f16* __restrict__ Bw,
    const float* __restrict__ gate_b,
    void* __restrict__ o0v, void* __restrict__ o1v) {
  constexpr int K = 1024;
  __shared__ __align__(16) f16 S[17920];  // 35840 B: K-loop uses 32KB, epi 34KB
  f16* As = S;
  f16* Bs = S + 8192;
  const int tid  = threadIdx.x;
  const int lane = tid & 63;
  const int quad = lane >> 4;
  const int wv   = tid >> 6;
  const int wrow = wv & 1, wcol = wv >> 1;
  const int n0 = blockIdx.y * 128;
  const int m0 = blockIdx.x * 128;

  const f16* ga[4];
  const f16* gb[4];
  f16* la[4];
  f16* lb[4];
#pragma unroll
  for (int j = 0; j < 4; ++j) {
    int s   = j * 256 + tid;           // 16B slot in [0,1024)
    int row = s >> 3;                  // tile row
    int kc  = (s & 7) ^ (row & 7);     // swizzled k-chunk (8 f16)
    ga[j] = A  + (size_t)(n0 + row) * K + kc * 8;
    gb[j] = Bw + (size_t)(m0 + row) * K + kc * 8;
    la[j] = &As[s * 8];
    lb[j] = &Bs[s * 8];
  }

  f32x4 acc[4][4];
#pragma unroll
  for (int mi = 0; mi < 4; ++mi)
#pragma unroll
    for (int ni = 0; ni < 4; ++ni) acc[mi][ni] = (f32x4){0.f, 0.f, 0.f, 0.f};

  for (int k0 = 0; k0 < K; k0 += 64) {
#pragma unroll
    for (int j = 0; j < 4; ++j) gload_lds16(ga[j], la[j]);
#pragma unroll
    for (int j = 0; j < 4; ++j) gload_lds16(gb[j], lb[j]);
#pragma unroll
    for (int j = 0; j < 4; ++j) { ga[j] += 64; gb[j] += 64; }
    __syncthreads();
#pragma unroll
    for (int kk = 0; kk < 2; ++kk) {
      f16x8 af[4], bfv[4];
#pragma unroll
      for (int mi = 0; mi < 4; ++mi) {
        int row  = wrow * 64 + mi * 16 + (lane & 15);
        int slot = row * 8 + ((kk * 4 + quad) ^ (row & 7));
        af[mi] = *(const f16x8*)(&As[slot * 8]);
      }
#pragma unroll
      for (int ni = 0; ni < 4; ++ni) {
        int row  = wcol * 64 + ni * 16 + (lane & 15);
        int slot = row * 8 + ((kk * 4 + quad) ^ (row & 7));
        bfv[ni] = *(const f16x8*)(&Bs[slot * 8]);
      }
#pragma unroll
      for (int mi = 0; mi < 4; ++mi)
#pragma unroll
        for (int ni = 0; ni < 4; ++ni)
          acc[mi][ni] = __builtin_amdgcn_mfma_f32_16x16x32_f16(
              af[mi], bfv[ni], acc[mi][ni], 0, 0, 0);
    }
    __syncthreads();
  }
  // K-loop's trailing __syncthreads: all waves done reading LDS; safe to reuse.

  if (EPI == 1) {
    // y fp32, direct stores (64B segments per 16-lane group)
#pragma unroll
    for (int mi = 0; mi < 4; ++mi)
#pragma unroll
      for (int ni = 0; ni < 4; ++ni) {
        const int m = m0 + wcol * 64 + ni * 16 + (lane & 15);
#pragma unroll
        for (int r = 0; r < 4; ++r) {
          const int n = n0 + wrow * 64 + mi * 16 + quad * 4 + r;
          ((float*)o0v)[(size_t)n * 1024 + m] = acc[mi][ni][r];
        }
      }
    return;
  }

  if (m0 < 1024) {
    // forget gate a: stage 128x128 f16, stride 136 (conflict-free)
#pragma unroll
    for (int mi = 0; mi < 4; ++mi)
#pragma unroll
      for (int ni = 0; ni < 4; ++ni) {
        const int ml = wcol * 64 + ni * 16 + (lane & 15);
#pragma unroll
        for (int r = 0; r < 4; ++r) {
          const int nl = wrow * 64 + mi * 16 + quad * 4 + r;
          S[nl * 136 + ml] = (f16)sigmoidf_(acc[mi][ni][r] + gate_b[m0 + ml]);
        }
      }
    __syncthreads();
    f16* o0 = (f16*)o0v;
#pragma unroll
    for (int i = 0; i < 8; ++i) {
      int ch = i * 256 + tid;
      int row = ch >> 4, cc = ch & 15;
      f16x8 vv = *(const f16x8*)&S[row * 136 + cc * 8];
      *(f16x8*)(o0 + (size_t)(n0 + row) * 1024 + m0 + cc * 8) = vv;
    }
  } else {
    // bv = sigmoid(bg + bias) * v : even lane bg, odd lane v (same channel)
    const int c0 = (m0 - 1024) >> 1;
#pragma unroll
    for (int mi = 0; mi < 4; ++mi)
#pragma unroll
      for (int ni = 0; ni < 4; ++ni) {
        const int ml = wcol * 64 + ni * 16 + (lane & 15);
#pragma unroll
        for (int r = 0; r < 4; ++r) {
          float val = acc[mi][ni][r];
          float pv = __shfl_xor(val, 1, 64);  // partner's value
          if (!(lane & 1)) {
            const int c = ml >> 1;  // local channel 0..63
            const int nl = wrow * 64 + mi * 16 + quad * 4 + r;
            S[nl * 72 + c] =
                (f16)(sigmoidf_(val + gate_b[1024 + c0 + c]) * pv);
          }
        }
      }
    __syncthreads();
    f16* o1 = (f16*)o1v;
#pragma unroll
    for (int i = 0; i < 4; ++i) {
      int ch = i * 256 + tid;
      int row = ch >> 3, cc = ch & 7;
      f16x8 vv = *(const f16x8*)&S[row * 72 + cc * 8];
      *(f16x8*)(o1 + (size_t)(n0 + row) * 1024 + c0 + cc * 8) = vv;
    }
  }
}

// ---------------- chunked scan: h_t = a_t*h_{t-1} + bv_t ----------------
// T=4096 = 128 chunks x 32; 2 channels/thread (f16x2).
__global__ __launch_bounds__(256) void scan_pass1(
    const f16x2* __restrict__ a, const f16x2* __restrict__ bv,
    float2* __restrict__ Ac, float2* __restrict__ Uc) {
  const int c2 = blockIdx.x * 256 + threadIdx.x;  // 0..511
  const int j = blockIdx.y;                       // 0..127
  const int b = blockIdx.z;
  const size_t base = ((size_t)(b * 4096 + j * 32)) * 512 + c2;
  float P0 = 1.f, P1 = 1.f, U0 = 0.f, U1 = 0.f;
#pragma unroll 8
  for (int t = 0; t < 32; ++t) {
    const size_t o = base + (size_t)t * 512;
    f16x2 at = a[o], bt = bv[o];
    float a0 = (float)at[0], a1 = (float)at[1];
    P0 *= a0; P1 *= a1;
    U0 = a0 * U0 + (float)bt[0];
    U1 = a1 * U1 + (float)bt[1];
  }
  const size_t o = ((size_t)(b * 128 + j)) * 512 + c2;
  Ac[o] = make_float2(P0, P1);
  Uc[o] = make_float2(U0, U1);
}

__global__ __launch_bounds__(256) void scan_pass2(
    const float* __restrict__ Ac, const float* __restrict__ Uc,
    const float* __restrict__ h_prev, float* __restrict__ Hs,
    float* __restrict__ hlast) {
  const int id = blockIdx.x * 256 + threadIdx.x;  // 0..4095
  const int b = id >> 10, c = id & 1023;
  float H = h_prev[b * 1024 + c];
  for (int j = 0; j < 128; ++j) {
    const size_t o = ((size_t)(b * 128 + j)) * 1024 + c;
    Hs[o] = H;
    H = Ac[o] * H + Uc[o];
  }
  hlast[b * 1024 + c] = H;
}

__global__ __launch_bounds__(256) void scan_pass3(
    const f16x2* __restrict__ a, const f16x2* __restrict__ bv,
    const float2* __restrict__ Hs, f16x2* __restrict__ hb) {
  const int c2 = blockIdx.x * 256 + threadIdx.x;
  const int j = blockIdx.y;
  const int b = blockIdx.z;
  const size_t base = ((size_t)(b * 4096 + j * 32)) * 512 + c2;
  float2 H = Hs[((size_t)(b * 128 + j)) * 512 + c2];
  float h0 = H.x, h1 = H.y;
#pragma unroll 8
  for (int t = 0; t < 32; ++t) {
    const size_t o = base + (size_t)t * 512;
    f16x2 at = a[o], bt = bv[o];
    h0 = (float)at[0] * h0 + (float)bt[0];
    h1 = (float)at[1] * h1 + (float)bt[1];
    f16x2 hv; hv[0] = (f16)h0; hv[1] = (f16)h1;
    hb[o] = hv;
  }
}

extern "C" void kernel_launch(void* const* d_in, const int* in_sizes, int n_in,
                              void* d_out, int out_size, void* d_ws,
                              size_t ws_size, hipStream_t stream) {
  const float* x       = (const float*)d_in[0];
  const float* h_prev  = (const float*)d_in[1];
  const float* gate_w  = (const float*)d_in[2];
  const float* gate_b  = (const float*)d_in[3];
  const float* value_w = (const float*)d_in[4];
  const float* out_w   = (const float*)d_in[5];
  float* out = (float*)d_out;

  char* ws = (char*)d_ws;
  // ws layout (bytes), total ~115.3 MB:
  f16*   xh   = (f16*)(ws);                    // 33,554,432  x f16; reused as h
  f16*   wgv  = (f16*)(ws + 33554432);         //  6,291,456  packed weights
  f16*   owb  = (f16*)(ws + 39845888);         //  2,097,152  out_w f16
  f16*   abuf = (f16*)(ws + 41943040);         // 33,554,432  forget gate a
  f16*   bvb  = (f16*)(ws + 75497472);         // 33,554,432  bv = bg*v
  float* Ac   = (float*)(ws + 109051904);      //  2,097,152
  float* Uc   = (float*)(ws + 111149056);      //  2,097,152
  float* Hs   = (float*)(ws + 113246208);      //  2,097,152
  float* hlast = out + 16777216;

  // fused cast + weight packing (1 launch)
  cast_pack<<<10240, 256, 0, stream>>>(x, gate_w, value_w, out_w, xh, wgv,
                                       owb);

  // gates+values GEMM, fused sigmoid + bv epilogue
  gemm_bt<0><<<dim3(24, 128), 256, 0, stream>>>(xh, wgv, gate_b, abuf, bvb);

  // chunked scan (128 chunks x 32)
  scan_pass1<<<dim3(2, 128, 4), 256, 0, stream>>>(
      (const f16x2*)abuf, (const f16x2*)bvb, (float2*)Ac, (float2*)Uc);
  scan_pass2<<<16, 256, 0, stream>>>(Ac, Uc, h_prev, Hs, hlast);
  scan_pass3<<<dim3(2, 128, 4), 256, 0, stream>>>(
      (const f16x2*)abuf, (const f16x2*)bvb, (const float2*)Hs, (f16x2*)xh);

  // output GEMM -> y fp32
  gemm_bt<1><<<dim3(8, 128), 256, 0, stream>>>(xh, owb, nullptr, out, nullptr);
}

// Round 4
// 360.478 us; speedup vs baseline: 1.1268x; 1.0356x over previous
//
#include <hip/hip_runtime.h>
#include <cstdint>
#include <cstddef>

// GLA layer: B=4, T=4096, D=1024, H=16, S=64
// fp16 pipeline, packed weights (a rows | interleaved bg/v rows).
// GEMM = 32x32x16 MFMA, 128x128 tile, BK=64, global_load_lds staging.
// GEMM1 epilogue: a = sigmoid(.), bv = sigmoid(.)*v (lane-pair shfl),
// LDS-staged f16x8 coalesced stores. Scan: 128 chunks x 32 steps,
// segment-parallel pass2. GEMM2 -> y fp32 (128B-segment direct stores).

typedef _Float16 f16;
typedef _Float16 f16x2 __attribute__((ext_vector_type(2)));
typedef _Float16 f16x8 __attribute__((ext_vector_type(8)));
typedef float    f32x16 __attribute__((ext_vector_type(16)));

__device__ __forceinline__ void gload_lds16(const void* g, void* l) {
  __builtin_amdgcn_global_load_lds(
      (const __attribute__((address_space(1))) void*)g,
      (__attribute__((address_space(3))) void*)l, 16, 0, 0);
}

__device__ __forceinline__ float sigmoidf_(float x) {
  return 1.0f / (1.0f + __expf(-x));
}

// ---------------- fused cast+pack fp32 -> fp16 ----------------
__global__ __launch_bounds__(256) void cast_pack(
    const float* __restrict__ x, const float* __restrict__ gw,
    const float* __restrict__ vw, const float* __restrict__ ow,
    f16* __restrict__ xh, f16* __restrict__ wgv, f16* __restrict__ owb) {
  const int XG = 2097152, GG = 262144, VG = 131072, OG = 131072;
  int id = blockIdx.x * 256 + threadIdx.x;
  const float* src;
  f16* dst;
  if (id < XG) {
    src = x + (size_t)id * 8;
    dst = xh + (size_t)id * 8;
  } else if (id < XG + GG) {
    int g = id - XG;
    int row = g >> 7, col = g & 127;
    int drow = (row < 1024) ? row : (1024 + 2 * (row - 1024));
    src = gw + ((size_t)row << 10) + col * 8;
    dst = wgv + ((size_t)drow << 10) + col * 8;
  } else if (id < XG + GG + VG) {
    int g = id - XG - GG;
    int row = g >> 7, col = g & 127;
    int drow = 1024 + 2 * row + 1;
    src = vw + ((size_t)row << 10) + col * 8;
    dst = wgv + ((size_t)drow << 10) + col * 8;
  } else if (id < XG + GG + VG + OG) {
    int g = id - XG - GG - VG;
    src = ow + (size_t)g * 8;
    dst = owb + (size_t)g * 8;
  } else {
    return;
  }
  float4 v0 = ((const float4*)src)[0], v1 = ((const float4*)src)[1];
  f16x8 o;
  o[0] = (f16)v0.x; o[1] = (f16)v0.y; o[2] = (f16)v0.z; o[3] = (f16)v0.w;
  o[4] = (f16)v1.x; o[5] = (f16)v1.y; o[6] = (f16)v1.z; o[7] = (f16)v1.w;
  *(f16x8*)dst = o;
}

// ------------- fp16 MFMA GEMM (32x32x16): C[N,M] = A[N,K] * B[M,K]^T -------
// 128x128 tile, BK=64, 4 waves (64x64 each = 2x2 of 32x32x16 MFMA).
template <int EPI>
__global__ __launch_bounds__(256, 3) void gemm_bt(
    const f16* __restrict__ A, const f16* __restrict__ Bw,
    const float* __restrict__ gate_b,
    void* __restrict__ o0v, void* __restrict__ o1v) {
  constexpr int K = 1024;
  __shared__ __align__(16) f16 S[17920];  // K-loop 32KB; a-epi 34.8KB
  f16* As = S;
  f16* Bs = S + 8192;
  const int tid  = threadIdx.x;
  const int lane = tid & 63;
  const int half = lane >> 5;        // 0/1: k-octet half for 32x32 frags
  const int l31  = lane & 31;
  const int wv   = tid >> 6;
  const int wrow = wv & 1, wcol = wv >> 1;
  const int n0 = blockIdx.y * 128;
  const int m0 = blockIdx.x * 128;

  const f16* ga[4];
  const f16* gb[4];
  f16* la[4];
  f16* lb[4];
#pragma unroll
  for (int j = 0; j < 4; ++j) {
    int s   = j * 256 + tid;           // 16B slot in [0,1024)
    int row = s >> 3;                  // tile row
    int kc  = (s & 7) ^ (row & 7);     // swizzled k-octet (8 f16)
    ga[j] = A  + (size_t)(n0 + row) * K + kc * 8;
    gb[j] = Bw + (size_t)(m0 + row) * K + kc * 8;
    la[j] = &As[s * 8];
    lb[j] = &Bs[s * 8];
  }

  f32x16 acc[2][2];
#pragma unroll
  for (int mi = 0; mi < 2; ++mi)
#pragma unroll
    for (int ni = 0; ni < 2; ++ni)
#pragma unroll
      for (int e = 0; e < 16; ++e) acc[mi][ni][e] = 0.f;

  for (int k0 = 0; k0 < K; k0 += 64) {
#pragma unroll
    for (int j = 0; j < 4; ++j) gload_lds16(ga[j], la[j]);
#pragma unroll
    for (int j = 0; j < 4; ++j) gload_lds16(gb[j], lb[j]);
#pragma unroll
    for (int j = 0; j < 4; ++j) { ga[j] += 64; gb[j] += 64; }
    __syncthreads();
#pragma unroll
    for (int kk = 0; kk < 4; ++kk) {   // 4 x K=16 steps
      f16x8 af[2], bfv[2];
#pragma unroll
      for (int mi = 0; mi < 2; ++mi) {
        int row  = wrow * 64 + mi * 32 + l31;
        int slot = row * 8 + ((kk * 2 + half) ^ (row & 7));
        af[mi] = *(const f16x8*)(&As[slot * 8]);
      }
#pragma unroll
      for (int ni = 0; ni < 2; ++ni) {
        int row  = wcol * 64 + ni * 32 + l31;
        int slot = row * 8 + ((kk * 2 + half) ^ (row & 7));
        bfv[ni] = *(const f16x8*)(&Bs[slot * 8]);
      }
#pragma unroll
      for (int mi = 0; mi < 2; ++mi)
#pragma unroll
        for (int ni = 0; ni < 2; ++ni)
          acc[mi][ni] = __builtin_amdgcn_mfma_f32_32x32x16_f16(
              af[mi], bfv[ni], acc[mi][ni], 0, 0, 0);
    }
    __syncthreads();
  }

  // C/D layout (32x32): col = l31, row = (r&3) + 8*(r>>2) + 4*half
  if (EPI == 1) {
#pragma unroll
    for (int mi = 0; mi < 2; ++mi)
#pragma unroll
      for (int ni = 0; ni < 2; ++ni) {
        const int m = m0 + wcol * 64 + ni * 32 + l31;
#pragma unroll
        for (int r = 0; r < 16; ++r) {
          const int n = n0 + wrow * 64 + mi * 32 + (r & 3) + 8 * (r >> 2) +
                        4 * half;
          ((float*)o0v)[(size_t)n * 1024 + m] = acc[mi][ni][r];
        }
      }
    return;
  }

  if (m0 < 1024) {
    // forget gate a: sigmoid, stage 128x128 f16 (stride 136)
#pragma unroll
    for (int mi = 0; mi < 2; ++mi)
#pragma unroll
      for (int ni = 0; ni < 2; ++ni) {
        const int ml = wcol * 64 + ni * 32 + l31;
        const float bias = gate_b[m0 + ml];
#pragma unroll
        for (int r = 0; r < 16; ++r) {
          const int nl = wrow * 64 + mi * 32 + (r & 3) + 8 * (r >> 2) +
                         4 * half;
          S[nl * 136 + ml] = (f16)sigmoidf_(acc[mi][ni][r] + bias);
        }
      }
    __syncthreads();
    f16* o0 = (f16*)o0v;
#pragma unroll
    for (int i = 0; i < 8; ++i) {
      int ch = i * 256 + tid;
      int row = ch >> 4, cc = ch & 15;
      f16x8 vv = *(const f16x8*)&S[row * 136 + cc * 8];
      *(f16x8*)(o0 + (size_t)(n0 + row) * 1024 + m0 + cc * 8) = vv;
    }
  } else {
    // bv = sigmoid(bg + bias) * v : even col bg, odd col v (same channel)
    const int c0 = (m0 - 1024) >> 1;
#pragma unroll
    for (int mi = 0; mi < 2; ++mi)
#pragma unroll
      for (int ni = 0; ni < 2; ++ni) {
        const int ml = wcol * 64 + ni * 32 + l31;
#pragma unroll
        for (int r = 0; r < 16; ++r) {
          float val = acc[mi][ni][r];
          float pv = __shfl_xor(val, 1, 64);  // partner's value
          if (!(lane & 1)) {
            const int c = ml >> 1;  // local channel 0..63
            const int nl = wrow * 64 + mi * 32 + (r & 3) + 8 * (r >> 2) +
                           4 * half;
            S[nl * 72 + c] =
                (f16)(sigmoidf_(val + gate_b[1024 + c0 + c]) * pv);
          }
        }
      }
    __syncthreads();
    f16* o1 = (f16*)o1v;
#pragma unroll
    for (int i = 0; i < 4; ++i) {
      int ch = i * 256 + tid;
      int row = ch >> 3, cc = ch & 7;
      f16x8 vv = *(const f16x8*)&S[row * 72 + cc * 8];
      *(f16x8*)(o1 + (size_t)(n0 + row) * 1024 + c0 + cc * 8) = vv;
    }
  }
}

// ---------------- chunked scan: h_t = a_t*h_{t-1} + bv_t ----------------
// T=4096 = 128 chunks x 32; 2 channels/thread (f16x2).
__global__ __launch_bounds__(256) void scan_pass1(
    const f16x2* __restrict__ a, const f16x2* __restrict__ bv,
    float2* __restrict__ Ac, float2* __restrict__ Uc) {
  const int c2 = blockIdx.x * 256 + threadIdx.x;  // 0..511
  const int j = blockIdx.y;                       // 0..127
  const int b = blockIdx.z;
  const size_t base = ((size_t)(b * 4096 + j * 32)) * 512 + c2;
  float P0 = 1.f, P1 = 1.f, U0 = 0.f, U1 = 0.f;
#pragma unroll 8
  for (int t = 0; t < 32; ++t) {
    const size_t o = base + (size_t)t * 512;
    f16x2 at = a[o], bt = bv[o];
    float a0 = (float)at[0], a1 = (float)at[1];
    P0 *= a0; P1 *= a1;
    U0 = a0 * U0 + (float)bt[0];
    U1 = a1 * U1 + (float)bt[1];
  }
  const size_t o = ((size_t)(b * 128 + j)) * 512 + c2;
  Ac[o] = make_float2(P0, P1);
  Uc[o] = make_float2(U0, U1);
}

// segment-parallel inter-chunk scan: 64 channels x 4 segments of 32 chunks
__global__ __launch_bounds__(256) void scan_pass2(
    const float* __restrict__ Ac, const float* __restrict__ Uc,
    const float* __restrict__ h_prev, float* __restrict__ Hs,
    float* __restrict__ hlast) {
  __shared__ float SA[4][64], SU[4][64];
  const int tid = threadIdx.x;
  const int seg = tid >> 6;            // 0..3
  const int cl  = tid & 63;
  const int ch  = blockIdx.x * 64 + cl;  // 0..4095
  const int b = ch >> 10, c = ch & 1023;
  float A = 1.f, U = 0.f;
  for (int t = 0; t < 32; ++t) {
    const int j = seg * 32 + t;
    const size_t o = ((size_t)(b * 128 + j)) * 1024 + c;
    float av = Ac[o], uv = Uc[o];
    U = av * U + uv;
    A = av * A;
  }
  SA[seg][cl] = A;
  SU[seg][cl] = U;
  __syncthreads();
  float Ae = 1.f, Ue = 0.f;
  for (int s = 0; s < seg; ++s) {
    float av = SA[s][cl], uv = SU[s][cl];
    Ue = av * Ue + uv;
    Ae = av * Ae;
  }
  float H = Ae * h_prev[b * 1024 + c] + Ue;  // state entering my segment
  for (int t = 0; t < 32; ++t) {
    const int j = seg * 32 + t;
    const size_t o = ((size_t)(b * 128 + j)) * 1024 + c;
    Hs[o] = H;
    H = Ac[o] * H + Uc[o];
  }
  if (seg == 3) hlast[b * 1024 + c] = H;
}

__global__ __launch_bounds__(256) void scan_pass3(
    const f16x2* __restrict__ a, const f16x2* __restrict__ bv,
    const float2* __restrict__ Hs, f16x2* __restrict__ hb) {
  const int c2 = blockIdx.x * 256 + threadIdx.x;
  const int j = blockIdx.y;
  const int b = blockIdx.z;
  const size_t base = ((size_t)(b * 4096 + j * 32)) * 512 + c2;
  float2 H = Hs[((size_t)(b * 128 + j)) * 512 + c2];
  float h0 = H.x, h1 = H.y;
#pragma unroll 8
  for (int t = 0; t < 32; ++t) {
    const size_t o = base + (size_t)t * 512;
    f16x2 at = a[o], bt = bv[o];
    h0 = (float)at[0] * h0 + (float)bt[0];
    h1 = (float)at[1] * h1 + (float)bt[1];
    f16x2 hv; hv[0] = (f16)h0; hv[1] = (f16)h1;
    hb[o] = hv;
  }
}

extern "C" void kernel_launch(void* const* d_in, const int* in_sizes, int n_in,
                              void* d_out, int out_size, void* d_ws,
                              size_t ws_size, hipStream_t stream) {
  const float* x       = (const float*)d_in[0];
  const float* h_prev  = (const float*)d_in[1];
  const float* gate_w  = (const float*)d_in[2];
  const float* gate_b  = (const float*)d_in[3];
  const float* value_w = (const float*)d_in[4];
  const float* out_w   = (const float*)d_in[5];
  float* out = (float*)d_out;

  char* ws = (char*)d_ws;
  // ws layout (bytes), total ~115.3 MB:
  f16*   xh   = (f16*)(ws);                    // 33,554,432  x f16; reused as h
  f16*   wgv  = (f16*)(ws + 33554432);         //  6,291,456  packed weights
  f16*   owb  = (f16*)(ws + 39845888);         //  2,097,152  out_w f16
  f16*   abuf = (f16*)(ws + 41943040);         // 33,554,432  forget gate a
  f16*   bvb  = (f16*)(ws + 75497472);         // 33,554,432  bv = bg*v
  float* Ac   = (float*)(ws + 109051904);      //  2,097,152
  float* Uc   = (float*)(ws + 111149056);      //  2,097,152
  float* Hs   = (float*)(ws + 113246208);      //  2,097,152
  float* hlast = out + 16777216;

  // fused cast + weight packing
  cast_pack<<<10240, 256, 0, stream>>>(x, gate_w, value_w, out_w, xh, wgv,
                                       owb);

  // gates+values GEMM, fused sigmoid + bv epilogue
  gemm_bt<0><<<dim3(24, 128), 256, 0, stream>>>(xh, wgv, gate_b, abuf, bvb);

  // chunked scan (128 chunks x 32)
  scan_pass1<<<dim3(2, 128, 4), 256, 0, stream>>>(
      (const f16x2*)abuf, (const f16x2*)bvb, (float2*)Ac, (float2*)Uc);
  scan_pass2<<<64, 256, 0, stream>>>(Ac, Uc, h_prev, Hs, hlast);
  scan_pass3<<<dim3(2, 128, 4), 256, 0, stream>>>(
      (const f16x2*)abuf, (const f16x2*)bvb, (const float2*)Hs, (f16x2*)xh);

  // output GEMM -> y fp32
  gemm_bt<1><<<dim3(8, 128), 256, 0, stream>>>(xh, owb, nullptr, out, nullptr);
}